// Round 4
// baseline (2770.754 us; speedup 1.0000x reference)
//
#include <hip/hip_runtime.h>
#include <hip/hip_bf16.h>

// CGCNN conv ×4 on MI355X — MFMA + streaming pass2.
// total[e][c] = F[e][c] + Pself[self[e]][c] + Pnbr[nbr[e]][c] + b[c]
//   F = nbr_fea @ W_nf  (mfma_f32_16x16x32_bf16, 16-edge tiles, K padded 41->64)
//   P = x @ [W_self | W_nbr] (MFMA), stored bf16 pair-interleaved:
//     Pu32[n*128 + half*64 + j] packs (col j, col j+64) of that half.
//   embed: x = atom @ embW + b (MFMA, K padded 92->96)
// Pass1 (edge1_k): BN1 stats in-register; stores total packed bf16x2 (T2).
// Pass2 (apply_k): stream T2, BN1 + sigmoid*softplus, atomic segment-sum.
// Fallback (ws too small): recompute pass2 (edge2_k).
// Fragment layouts (guide §3, m89-verified):
//   A: row=lane&15, k=(lane>>4)*8+j ;  B: col=lane&15, k=(lane>>4)*8+j
//   D: col=lane&15, row=(lane>>4)*4+reg
// NOTE: E=800000, N=50000 are multiples of 16 (no tail guards in tiled paths).

typedef __attribute__((ext_vector_type(8))) short short8;
typedef __attribute__((ext_vector_type(4))) float f32x4;

__device__ __forceinline__ float softplus_f(float x) {
  return fmaxf(x, 0.f) + log1pf(__expf(-fabsf(x)));
}
__device__ __forceinline__ float sigmoid_f(float x) {
  return 1.f / (1.f + __expf(-x));
}
__device__ __forceinline__ ushort f2b(float f) {
  __hip_bfloat16 h = __float2bfloat16(f);
  return *reinterpret_cast<ushort*>(&h);
}
__device__ __forceinline__ float b2f(ushort u) {
  return __uint_as_float(((unsigned)u) << 16);
}

// ---- one-time: fc_W -> B-fragments (edge + P GEMMs), emb_W -> B-fragments ----
// WBe[layer][cb<8][s<2][lane][8] : edge GEMM B (rows 128+k, k zero-padded to 64)
// WBp[layer][cb<16][s<2][lane][8]: P GEMM B (K=64; col<128 -> Wself else Wnbr)
// WBm[cb<4][s<3][lane][8]        : embed GEMM B (K zero-padded 92->96)
__global__ void wconv_k(const float* __restrict__ fcW, const float* __restrict__ embW,
                        ushort* __restrict__ WBe, ushort* __restrict__ WBp,
                        ushort* __restrict__ WBm) {
  const int tid = blockIdx.x * 256 + threadIdx.x;  // 12288 fc + 768 emb
  if (tid >= 13056) return;
  if (tid < 12288) {
    const int layer = tid / 3072;
    const int rem = tid % 3072;
    const int unit = rem / 64;
    const int lane = rem % 64;
    const int c16 = lane & 15, r4 = lane >> 4;
    const float* W = fcW + (size_t)layer * 169 * 128;
    if (unit < 16) {
      const int cb = unit >> 1, s = unit & 1;
      ushort* dst = WBe + (((size_t)(layer * 8 + cb) * 2 + s) * 64 + lane) * 8;
#pragma unroll
      for (int j = 0; j < 8; ++j) {
        const int k = s * 32 + r4 * 8 + j;
        dst[j] = f2b(k < 41 ? W[(128 + k) * 128 + cb * 16 + c16] : 0.f);
      }
    } else {
      const int pu = unit - 16;
      const int cb = pu >> 1, s = pu & 1;
      const int c256 = cb * 16 + c16;
      ushort* dst = WBp + (((size_t)(layer * 16 + cb) * 2 + s) * 64 + lane) * 8;
#pragma unroll
      for (int j = 0; j < 8; ++j) {
        const int k = s * 32 + r4 * 8 + j;
        const int row = (c256 < 128) ? k : 64 + k;
        dst[j] = f2b(W[row * 128 + (c256 & 127)]);
      }
    }
  } else {
    const int r = tid - 12288;  // 0..767
    const int unit = r / 64, lane = r % 64;
    const int cb = unit / 3, s = unit % 3;
    const int c16 = lane & 15, r4 = lane >> 4;
    ushort* dst = WBm + ((size_t)(cb * 3 + s) * 64 + lane) * 8;
#pragma unroll
    for (int j = 0; j < 8; ++j) {
      const int k = s * 32 + r4 * 8 + j;
      dst[j] = f2b(k < 92 ? embW[k * 64 + cb * 16 + c16] : 0.f);
    }
  }
}

// ---- one-time: nbr_fea -> bf16 A-fragment tiles [t][s][lane][8] ----
__global__ void nbrconv_k(const float* __restrict__ nbr, ushort* __restrict__ nbrT,
                          int ntiles, int E) {
  const long tid = (long)blockIdx.x * 256 + threadIdx.x;
  if (tid >= (long)ntiles * 128) return;
  const long t = tid >> 7;
  const int rem = (int)(tid & 127);
  const int s = rem >> 6, lane = rem & 63;
  const int c16 = lane & 15, r4 = lane >> 4;
  long e = t * 16 + c16;
  if (e >= E) e = E - 1;
  ushort* dst = nbrT + ((t * 2 + s) * 64 + lane) * 8;
#pragma unroll
  for (int j = 0; j < 8; ++j) {
    const int k = s * 32 + r4 * 8 + j;
    dst[j] = f2b(k < 41 ? nbr[e * 41 + k] : 0.f);
  }
}

// ---- embed via MFMA: x = atom @ embW + b ; writes f32 x and bf16 xb ----
__global__ __launch_bounds__(256, 4)
void embed_mfma_k(const float* __restrict__ atom, const ushort* __restrict__ WBm,
                  const float* __restrict__ b, float* __restrict__ x,
                  ushort* __restrict__ xb, int ntilesN) {
  const int lane = threadIdx.x & 63;
  const int c16 = lane & 15, r4 = lane >> 4;
  const long nw = (long)gridDim.x * 4;
  const f32x4 vz = {0.f, 0.f, 0.f, 0.f};
  short8 wb[4][3];
#pragma unroll
  for (int cb = 0; cb < 4; ++cb)
#pragma unroll
    for (int s = 0; s < 3; ++s)
      wb[cb][s] = *reinterpret_cast<const short8*>(WBm + ((size_t)(cb * 3 + s) * 64 + lane) * 8);
  float bias[4];
#pragma unroll
  for (int cb = 0; cb < 4; ++cb) bias[cb] = b[cb * 16 + c16];
  for (long t = (long)blockIdx.x * 4 + (threadIdx.x >> 6); t < ntilesN; t += nw) {
    const float* __restrict__ ar = atom + (t * 16 + c16) * 92;
    short8 a[3];
#pragma unroll
    for (int s = 0; s < 3; ++s)
#pragma unroll
      for (int j = 0; j < 8; ++j) {
        const int k = s * 32 + r4 * 8 + j;
        a[s][j] = (short)f2b(k < 92 ? ar[k] : 0.f);
      }
    f32x4 acc[4];
#pragma unroll
    for (int cb = 0; cb < 4; ++cb) {
      acc[cb] = vz;
#pragma unroll
      for (int s = 0; s < 3; ++s)
        acc[cb] = __builtin_amdgcn_mfma_f32_16x16x32_bf16(a[s], wb[cb][s], acc[cb], 0, 0, 0);
    }
#pragma unroll
    for (int cb = 0; cb < 4; ++cb)
#pragma unroll
      for (int r = 0; r < 4; ++r) {
        const long node = t * 16 + r4 * 4 + r;
        const float v = acc[cb][r] + bias[cb];
        x[node * 64 + cb * 16 + c16] = v;
        xb[node * 64 + cb * 16 + c16] = f2b(v);
      }
  }
}

// ---- P = xb @ WBp (MFMA); one wave per (node-tile, half); pair-packed store ----
__global__ __launch_bounds__(256, 2)
void p_k(const ushort* __restrict__ xb, const ushort* __restrict__ WBp,
         unsigned* __restrict__ Pu, int ntilesN) {
  const int lane = threadIdx.x & 63;
  const int c16 = lane & 15, r4 = lane >> 4;
  const long nw = (long)gridDim.x * 4;
  const f32x4 vz = {0.f, 0.f, 0.f, 0.f};
  for (long u = (long)blockIdx.x * 4 + (threadIdx.x >> 6); u < 2L * ntilesN; u += nw) {
    const long t = u >> 1;
    const int h = (int)(u & 1);
    short8 a[2];
#pragma unroll
    for (int s = 0; s < 2; ++s)
      a[s] = *reinterpret_cast<const short8*>(xb + (t * 16 + c16) * 64 + s * 32 + r4 * 8);
    f32x4 acc[8];
#pragma unroll
    for (int cb = 0; cb < 8; ++cb) {
      acc[cb] = vz;
#pragma unroll
      for (int s = 0; s < 2; ++s) {
        const short8 bfr = *reinterpret_cast<const short8*>(
            WBp + (((size_t)(h * 8 + cb) * 2 + s) * 64 + lane) * 8);
        acc[cb] = __builtin_amdgcn_mfma_f32_16x16x32_bf16(a[s], bfr, acc[cb], 0, 0, 0);
      }
    }
#pragma unroll
    for (int jb = 0; jb < 4; ++jb)
#pragma unroll
      for (int r = 0; r < 4; ++r) {
        const long node = t * 16 + r4 * 4 + r;
        const unsigned lo = f2b(acc[jb][r]);
        const unsigned hi = f2b(acc[jb + 4][r]);
        Pu[node * 128 + h * 64 + jb * 16 + c16] = lo | (hi << 16);
      }
  }
}

// ---- pass1: BN1 stats (+ optional packed bf16 T2 store). idx prefetched. ----
template <bool STORE>
__global__ __launch_bounds__(256, 2)
void edge1_k(const ushort* __restrict__ nbrT, const ushort* __restrict__ WBe,
             const unsigned* __restrict__ Pu, const int* __restrict__ self_idx,
             const int* __restrict__ nbr_idx, const float* __restrict__ fcb,
             float* __restrict__ stats, unsigned* __restrict__ T2, int ntiles) {
  const int tid = threadIdx.x;
  const int lane = tid & 63;
  const int c16 = lane & 15, r4 = lane >> 4;
  const long nw = (long)gridDim.x * 4;
  const f32x4 vz = {0.f, 0.f, 0.f, 0.f};

  short8 wb[8][2];
#pragma unroll
  for (int cb = 0; cb < 8; ++cb)
#pragma unroll
    for (int s = 0; s < 2; ++s)
      wb[cb][s] = *reinterpret_cast<const short8*>(WBe + (((size_t)cb * 2 + s) * 64 + lane) * 8);
  float bias[8];
#pragma unroll
  for (int cb = 0; cb < 8; ++cb) bias[cb] = fcb[cb * 16 + c16];
  float sum[8], ssq[8];
#pragma unroll
  for (int cb = 0; cb < 8; ++cb) { sum[cb] = 0.f; ssq[cb] = 0.f; }

  long t = (long)blockIdx.x * 4 + (tid >> 6);
  int se[4], ne[4];
  if (t < ntiles) {
#pragma unroll
    for (int r = 0; r < 4; ++r) {
      se[r] = self_idx[t * 16 + r4 * 4 + r];
      ne[r] = nbr_idx[t * 16 + r4 * 4 + r];
    }
  }
  while (t < ntiles) {
    // current tile A-fragments (address dep on t only)
    const short8 a0 = *reinterpret_cast<const short8*>(nbrT + (t * 2) * 512 + lane * 8);
    const short8 a1 = *reinterpret_cast<const short8*>(nbrT + (t * 2 + 1) * 512 + lane * 8);
    // issue all 32 gathers (indices prefetched last iteration)
    unsigned gs[4][4], gn[4][4];
#pragma unroll
    for (int jb = 0; jb < 4; ++jb)
#pragma unroll
      for (int r = 0; r < 4; ++r) {
        gs[jb][r] = Pu[(long)se[r] * 128 + jb * 16 + c16];
        gn[jb][r] = Pu[(long)ne[r] * 128 + 64 + jb * 16 + c16];
      }
    // prefetch next tile's indices (breaks idx->gather serial chain)
    const long t2 = t + nw;
    int se2[4] = {0, 0, 0, 0}, ne2[4] = {0, 0, 0, 0};
    if (t2 < ntiles) {
#pragma unroll
      for (int r = 0; r < 4; ++r) {
        se2[r] = self_idx[t2 * 16 + r4 * 4 + r];
        ne2[r] = nbr_idx[t2 * 16 + r4 * 4 + r];
      }
    }
    // MFMA while gathers are in flight
    f32x4 acc[8];
#pragma unroll
    for (int cb = 0; cb < 8; ++cb) {
      acc[cb] = __builtin_amdgcn_mfma_f32_16x16x32_bf16(a0, wb[cb][0], vz, 0, 0, 0);
      acc[cb] = __builtin_amdgcn_mfma_f32_16x16x32_bf16(a1, wb[cb][1], acc[cb], 0, 0, 0);
    }
#pragma unroll
    for (int jb = 0; jb < 4; ++jb)
#pragma unroll
      for (int r = 0; r < 4; ++r) {
        const unsigned ds = gs[jb][r], dn = gn[jb][r];
        const float tf = acc[jb][r]     + b2f((ushort)ds)         + b2f((ushort)dn)         + bias[jb];
        const float tc = acc[jb + 4][r] + b2f((ushort)(ds >> 16)) + b2f((ushort)(dn >> 16)) + bias[jb + 4];
        sum[jb] += tf;     ssq[jb]     = fmaf(tf, tf, ssq[jb]);
        sum[jb + 4] += tc; ssq[jb + 4] = fmaf(tc, tc, ssq[jb + 4]);
        if (STORE)
          T2[(t * 16 + r4 * 4 + r) * 64 + jb * 16 + c16] =
              (unsigned)f2b(tf) | ((unsigned)f2b(tc) << 16);
      }
    t = t2;
#pragma unroll
    for (int r = 0; r < 4; ++r) { se[r] = se2[r]; ne[r] = ne2[r]; }
  }

#pragma unroll
  for (int cb = 0; cb < 8; ++cb) {
    float s = sum[cb], q = ssq[cb];
    s += __shfl_xor(s, 16); q += __shfl_xor(q, 16);
    s += __shfl_xor(s, 32); q += __shfl_xor(q, 32);
    if (lane < 16) {
      atomicAdd(&stats[cb * 16 + lane], s);
      atomicAdd(&stats[128 + cb * 16 + lane], q);
    }
  }
}

// ---- pass2 (stored path): stream T2, BN1 + activation, atomic segment-sum ----
__global__ __launch_bounds__(256, 4)
void apply_k(const unsigned* __restrict__ T2, const int* __restrict__ self_idx,
             const float* __restrict__ stats, float* __restrict__ summed, long total) {
  const int j = threadIdx.x & 63;  // constant across grid-stride (stride % 64 == 0)
  const float scf = stats[256 + j], shf = stats[384 + j];
  const float scc = stats[320 + j], shc = stats[448 + j];
  const long stride = (long)gridDim.x * 256;
  for (long idx = (long)blockIdx.x * 256 + threadIdx.x; idx < total; idx += stride) {
    const long e = idx >> 6;  // wave-uniform
    const unsigned u = T2[idx];
    const int s = self_idx[e];
    const float uf = fmaf(b2f((ushort)u), scf, shf);
    const float uc = fmaf(b2f((ushort)(u >> 16)), scc, shc);
    atomicAdd(&summed[(long)s * 64 + j], sigmoid_f(uf) * softplus_f(uc));
  }
}

// ---- pass2 fallback (no T2): recompute + apply + segment-sum ----
__global__ __launch_bounds__(256, 2)
void edge2_k(const ushort* __restrict__ nbrT, const ushort* __restrict__ WBe,
             const unsigned* __restrict__ Pu, const int* __restrict__ self_idx,
             const int* __restrict__ nbr_idx, const float* __restrict__ fcb,
             const float* __restrict__ stats, float* __restrict__ summed, int ntiles) {
  const int tid = threadIdx.x;
  const int lane = tid & 63;
  const int c16 = lane & 15, r4 = lane >> 4;
  const long nw = (long)gridDim.x * 4;
  const f32x4 vz = {0.f, 0.f, 0.f, 0.f};
  short8 wb[8][2];
#pragma unroll
  for (int cb = 0; cb < 8; ++cb)
#pragma unroll
    for (int s = 0; s < 2; ++s)
      wb[cb][s] = *reinterpret_cast<const short8*>(WBe + (((size_t)cb * 2 + s) * 64 + lane) * 8);
  float bias[8], sc[8], sh[8];
#pragma unroll
  for (int cb = 0; cb < 8; ++cb) {
    bias[cb] = fcb[cb * 16 + c16];
    sc[cb] = stats[256 + cb * 16 + c16];
    sh[cb] = stats[384 + cb * 16 + c16];
  }
  for (long t = (long)blockIdx.x * 4 + (tid >> 6); t < ntiles; t += nw) {
    const short8 a0 = *reinterpret_cast<const short8*>(nbrT + (t * 2) * 512 + lane * 8);
    const short8 a1 = *reinterpret_cast<const short8*>(nbrT + (t * 2 + 1) * 512 + lane * 8);
    int se[4], ne[4];
#pragma unroll
    for (int r = 0; r < 4; ++r) {
      se[r] = self_idx[t * 16 + r4 * 4 + r];
      ne[r] = nbr_idx[t * 16 + r4 * 4 + r];
    }
    f32x4 acc[8];
#pragma unroll
    for (int cb = 0; cb < 8; ++cb) {
      acc[cb] = __builtin_amdgcn_mfma_f32_16x16x32_bf16(a0, wb[cb][0], vz, 0, 0, 0);
      acc[cb] = __builtin_amdgcn_mfma_f32_16x16x32_bf16(a1, wb[cb][1], acc[cb], 0, 0, 0);
    }
#pragma unroll
    for (int jb = 0; jb < 4; ++jb)
#pragma unroll
      for (int r = 0; r < 4; ++r) {
        const unsigned ds = Pu[(long)se[r] * 128 + jb * 16 + c16];
        const unsigned dn = Pu[(long)ne[r] * 128 + 64 + jb * 16 + c16];
        const float tf = acc[jb][r]     + b2f((ushort)ds)         + b2f((ushort)dn)         + bias[jb];
        const float tc = acc[jb + 4][r] + b2f((ushort)(ds >> 16)) + b2f((ushort)(dn >> 16)) + bias[jb + 4];
        const float uf = fmaf(tf, sc[jb], sh[jb]);
        const float uc = fmaf(tc, sc[jb + 4], sh[jb + 4]);
        atomicAdd(&summed[(long)se[r] * 64 + jb * 16 + c16], sigmoid_f(uf) * softplus_f(uc));
      }
  }
}

__global__ void fin1_k(float* __restrict__ stats, const float* __restrict__ g,
                       const float* __restrict__ b, int E) {
  const int c = threadIdx.x;  // 0..127
  const float mean = stats[c] / (float)E;
  const float var = stats[128 + c] / (float)E - mean * mean;
  const float sc = g[c] * rsqrtf(var + 1e-5f);
  stats[256 + c] = sc;
  stats[384 + c] = fmaf(-mean, sc, b[c]);
}

__global__ void bn2_stats_k(const float* __restrict__ summed, float* __restrict__ stats, int N) {
  const int tid = threadIdx.x;
  const int j = tid & 63;
  const int r = tid >> 6;
  float s = 0.f, q = 0.f;
  for (long n = (long)blockIdx.x * 4 + r; n < N; n += (long)gridDim.x * 4) {
    const float v = summed[n * 64 + j];
    s += v; q = fmaf(v, v, q);
  }
  __shared__ float2 red[256];
  red[tid] = make_float2(s, q);
  __syncthreads();
  if (tid < 64) {
    const float2 a = red[tid], b2 = red[tid + 64], c = red[tid + 128], d = red[tid + 192];
    atomicAdd(&stats[512 + tid], a.x + b2.x + c.x + d.x);
    atomicAdd(&stats[576 + tid], a.y + b2.y + c.y + d.y);
  }
}

__global__ void fin2_k(float* __restrict__ stats, const float* __restrict__ g,
                       const float* __restrict__ b, int N) {
  const int c = threadIdx.x;  // 0..63
  const float mean = stats[512 + c] / (float)N;
  const float var = stats[576 + c] / (float)N - mean * mean;
  const float sc = g[c] * rsqrtf(var + 1e-5f);
  stats[640 + c] = sc;
  stats[704 + c] = fmaf(-mean, sc, b[c]);
}

__global__ void upd_k(const float* __restrict__ x, const float* __restrict__ summed,
                      const float* __restrict__ stats, float* __restrict__ dst,
                      ushort* __restrict__ xb, int total) {
  const int idx = blockIdx.x * 256 + threadIdx.x;
  if (idx >= total) return;
  const int j = idx & 63;
  const float v = softplus_f(x[idx] + fmaf(summed[idx], stats[640 + j], stats[704 + j]));
  dst[idx] = v;
  xb[idx] = f2b(v);
}

extern "C" void kernel_launch(void* const* d_in, const int* in_sizes, int n_in,
                              void* d_out, int out_size, void* d_ws, size_t ws_size,
                              hipStream_t stream) {
  const float* atom_fea = (const float*)d_in[0];
  const float* nbr_fea  = (const float*)d_in[1];
  const int*   self_idx = (const int*)d_in[2];
  const int*   nbr_idx  = (const int*)d_in[3];
  const float* emb_W    = (const float*)d_in[4];
  const float* emb_b    = (const float*)d_in[5];
  const float* fc_W     = (const float*)d_in[6];
  const float* fc_b     = (const float*)d_in[7];
  const float* bn1_g    = (const float*)d_in[8];
  const float* bn1_b    = (const float*)d_in[9];
  const float* bn2_g    = (const float*)d_in[10];
  const float* bn2_b    = (const float*)d_in[11];
  float* out = (float*)d_out;

  const int N = in_sizes[0] / 92;
  const int E = in_sizes[2];
  const int ntilesE = (E + 15) / 16;
  const int ntilesN = (N + 15) / 16;

  unsigned char* base = (unsigned char*)d_ws;
  float* x      = (float*)base;                        base += (size_t)N * 64 * 4;
  unsigned* Pu  = (unsigned*)base;                     base += (size_t)N * 128 * 4;
  float* summed = (float*)base;                        base += (size_t)N * 64 * 4;
  float* stats  = (float*)base;                        base += 768 * 4;
  ushort* xb    = (ushort*)base;                       base += (size_t)N * 64 * 2;
  ushort* nbrT  = (ushort*)base;                       base += (size_t)ntilesE * 1024 * 2;
  ushort* WBe   = (ushort*)base;                       base += 32768 * 2;
  ushort* WBp   = (ushort*)base;                       base += 65536 * 2;
  ushort* WBm   = (ushort*)base;                       base += 6144 * 2;
  unsigned* T2  = (unsigned*)base;                     base += (size_t)E * 64 * 4;
  const bool store = (size_t)(base - (unsigned char*)d_ws) <= ws_size;

  wconv_k<<<51, 256, 0, stream>>>(fc_W, emb_W, WBe, WBp, WBm);
  nbrconv_k<<<(ntilesE * 128 + 255) / 256, 256, 0, stream>>>(nbr_fea, nbrT, ntilesE, E);
  embed_mfma_k<<<512, 256, 0, stream>>>(atom_fea, WBm, emb_b, x, xb, ntilesN);

  for (int i = 0; i < 4; ++i) {
    const ushort* WBei = WBe + (size_t)i * 8192;
    const ushort* WBpi = WBp + (size_t)i * 16384;
    const float* bi = fc_b + (size_t)i * 128;
    hipMemsetAsync(summed, 0, ((size_t)N * 64 + 768) * sizeof(float), stream);
    p_k<<<1024, 256, 0, stream>>>(xb, WBpi, Pu, ntilesN);
    if (store)
      edge1_k<true><<<4096, 256, 0, stream>>>(nbrT, WBei, Pu, self_idx, nbr_idx, bi, stats, T2, ntilesE);
    else
      edge1_k<false><<<4096, 256, 0, stream>>>(nbrT, WBei, Pu, self_idx, nbr_idx, bi, stats, T2, ntilesE);
    fin1_k<<<1, 128, 0, stream>>>(stats, bn1_g + (size_t)i * 128, bn1_b + (size_t)i * 128, E);
    if (store)
      apply_k<<<2048, 256, 0, stream>>>(T2, self_idx, stats, summed, (long)E * 64);
    else
      edge2_k<<<2048, 256, 0, stream>>>(nbrT, WBei, Pu, self_idx, nbr_idx, bi, stats, summed, ntilesE);
    bn2_stats_k<<<256, 256, 0, stream>>>(summed, stats, N);
    fin2_k<<<1, 64, 0, stream>>>(stats, bn2_g + (size_t)i * 64, bn2_b + (size_t)i * 64, N);
    float* dst = (i == 3) ? out : x;
    upd_k<<<(N * 64 + 255) / 256, 256, 0, stream>>>(x, summed, stats, dst, xb, N * 64);
  }
}

// Round 5
// 2468.495 us; speedup vs baseline: 1.1224x; 1.1224x over previous
//
#include <hip/hip_runtime.h>
#include <hip/hip_bf16.h>

// CGCNN conv ×4 on MI355X — MFMA, recompute both edge passes, LDS weights.
// total[e][c] = F[e][c] + Pself[self[e]][c] + Pnbr[nbr[e]][c] + b[c]
//   F = nbr_fea @ W_nf  (mfma_f32_16x16x32_bf16, 16-edge tiles, K 41->64)
//   P = x @ [W_self | W_nbr] (MFMA), bf16 pair-interleaved:
//     Pu32[n*128 + half*64 + j] packs (col j, col j+64) of that half.
// BN1 trick: per-column fc bias does not change var and shifts mean linearly,
// so edge passes compute t' (no bias); fin1 folds bias into scale/shift.
// Pass1 (MODE 1): per-column sum/ssq of t'. Pass2 (MODE 2): u = t'*sc+sh,
// msg = sigmoid(u_f)*softplus(u_c), atomic segment-sum.
// Fragment layouts (guide §3, m89-verified):
//   A: row=lane&15, k=(lane>>4)*8+j ;  B: col=lane&15, k=(lane>>4)*8+j
//   D: col=lane&15, row=(lane>>4)*4+reg
// E, N are multiples of 16 (E=800000, N=50000).

typedef __attribute__((ext_vector_type(8))) short short8;
typedef __attribute__((ext_vector_type(4))) float f32x4;

__device__ __forceinline__ float softplus_f(float x) {
  return fmaxf(x, 0.f) + log1pf(__expf(-fabsf(x)));
}
__device__ __forceinline__ float sigmoid_f(float x) {
  return 1.f / (1.f + __expf(-x));
}
__device__ __forceinline__ ushort f2b(float f) {
  __hip_bfloat16 h = __float2bfloat16(f);
  return *reinterpret_cast<ushort*>(&h);
}
__device__ __forceinline__ float b2f(ushort u) {
  return __uint_as_float(((unsigned)u) << 16);
}

// ---- one-time: fc_W -> B-fragments (edge + P GEMMs), emb_W -> B-fragments ----
__global__ void wconv_k(const float* __restrict__ fcW, const float* __restrict__ embW,
                        ushort* __restrict__ WBe, ushort* __restrict__ WBp,
                        ushort* __restrict__ WBm) {
  const int tid = blockIdx.x * 256 + threadIdx.x;  // 12288 fc + 768 emb
  if (tid >= 13056) return;
  if (tid < 12288) {
    const int layer = tid / 3072;
    const int rem = tid % 3072;
    const int unit = rem / 64;
    const int lane = rem % 64;
    const int c16 = lane & 15, r4 = lane >> 4;
    const float* W = fcW + (size_t)layer * 169 * 128;
    if (unit < 16) {
      const int cb = unit >> 1, s = unit & 1;
      ushort* dst = WBe + (((size_t)(layer * 8 + cb) * 2 + s) * 64 + lane) * 8;
#pragma unroll
      for (int j = 0; j < 8; ++j) {
        const int k = s * 32 + r4 * 8 + j;
        dst[j] = f2b(k < 41 ? W[(128 + k) * 128 + cb * 16 + c16] : 0.f);
      }
    } else {
      const int pu = unit - 16;
      const int cb = pu >> 1, s = pu & 1;
      const int c256 = cb * 16 + c16;
      ushort* dst = WBp + (((size_t)(layer * 16 + cb) * 2 + s) * 64 + lane) * 8;
#pragma unroll
      for (int j = 0; j < 8; ++j) {
        const int k = s * 32 + r4 * 8 + j;
        const int row = (c256 < 128) ? k : 64 + k;
        dst[j] = f2b(W[row * 128 + (c256 & 127)]);
      }
    }
  } else {
    const int r = tid - 12288;  // 0..767
    const int unit = r / 64, lane = r % 64;
    const int cb = unit / 3, s = unit % 3;
    const int c16 = lane & 15, r4 = lane >> 4;
    ushort* dst = WBm + ((size_t)(cb * 3 + s) * 64 + lane) * 8;
#pragma unroll
    for (int j = 0; j < 8; ++j) {
      const int k = s * 32 + r4 * 8 + j;
      dst[j] = f2b(k < 92 ? embW[k * 64 + cb * 16 + c16] : 0.f);
    }
  }
}

// ---- one-time: nbr_fea -> bf16 A-fragment tiles [t][s][lane][8] ----
__global__ void nbrconv_k(const float* __restrict__ nbr, ushort* __restrict__ nbrT,
                          int ntiles, int E) {
  const long tid = (long)blockIdx.x * 256 + threadIdx.x;
  if (tid >= (long)ntiles * 128) return;
  const long t = tid >> 7;
  const int rem = (int)(tid & 127);
  const int s = rem >> 6, lane = rem & 63;
  const int c16 = lane & 15, r4 = lane >> 4;
  long e = t * 16 + c16;
  if (e >= E) e = E - 1;
  ushort* dst = nbrT + ((t * 2 + s) * 64 + lane) * 8;
#pragma unroll
  for (int j = 0; j < 8; ++j) {
    const int k = s * 32 + r4 * 8 + j;
    dst[j] = f2b(k < 41 ? nbr[e * 41 + k] : 0.f);
  }
}

// ---- embed via MFMA: x = atom @ embW + b ; writes f32 x and bf16 xb ----
__global__ __launch_bounds__(256, 4)
void embed_mfma_k(const float* __restrict__ atom, const ushort* __restrict__ WBm,
                  const float* __restrict__ b, float* __restrict__ x,
                  ushort* __restrict__ xb, int ntilesN) {
  const int lane = threadIdx.x & 63;
  const int c16 = lane & 15, r4 = lane >> 4;
  const long nw = (long)gridDim.x * 4;
  const f32x4 vz = {0.f, 0.f, 0.f, 0.f};
  short8 wb[4][3];
#pragma unroll
  for (int cb = 0; cb < 4; ++cb)
#pragma unroll
    for (int s = 0; s < 3; ++s)
      wb[cb][s] = *reinterpret_cast<const short8*>(WBm + ((size_t)(cb * 3 + s) * 64 + lane) * 8);
  float bias[4];
#pragma unroll
  for (int cb = 0; cb < 4; ++cb) bias[cb] = b[cb * 16 + c16];
  for (long t = (long)blockIdx.x * 4 + (threadIdx.x >> 6); t < ntilesN; t += nw) {
    const float* __restrict__ ar = atom + (t * 16 + c16) * 92;
    short8 a[3];
#pragma unroll
    for (int s = 0; s < 3; ++s)
#pragma unroll
      for (int j = 0; j < 8; ++j) {
        const int k = s * 32 + r4 * 8 + j;
        a[s][j] = (short)f2b(k < 92 ? ar[k] : 0.f);
      }
    f32x4 acc[4];
#pragma unroll
    for (int cb = 0; cb < 4; ++cb) {
      acc[cb] = vz;
#pragma unroll
      for (int s = 0; s < 3; ++s)
        acc[cb] = __builtin_amdgcn_mfma_f32_16x16x32_bf16(a[s], wb[cb][s], acc[cb], 0, 0, 0);
    }
#pragma unroll
    for (int cb = 0; cb < 4; ++cb)
#pragma unroll
      for (int r = 0; r < 4; ++r) {
        const long node = t * 16 + r4 * 4 + r;
        const float v = acc[cb][r] + bias[cb];
        x[node * 64 + cb * 16 + c16] = v;
        xb[node * 64 + cb * 16 + c16] = f2b(v);
      }
  }
}

// ---- P = xb @ WBp (MFMA); one wave per (node-tile, half); pair-packed store ----
__global__ __launch_bounds__(256, 4)
void p_k(const ushort* __restrict__ xb, const ushort* __restrict__ WBp,
         unsigned* __restrict__ Pu, int ntilesN) {
  const int lane = threadIdx.x & 63;
  const int c16 = lane & 15, r4 = lane >> 4;
  const long nw = (long)gridDim.x * 4;
  const f32x4 vz = {0.f, 0.f, 0.f, 0.f};
  for (long u = (long)blockIdx.x * 4 + (threadIdx.x >> 6); u < 2L * ntilesN; u += nw) {
    const long t = u >> 1;
    const int h = (int)(u & 1);
    short8 a[2];
#pragma unroll
    for (int s = 0; s < 2; ++s)
      a[s] = *reinterpret_cast<const short8*>(xb + (t * 16 + c16) * 64 + s * 32 + r4 * 8);
    f32x4 acc[8];
#pragma unroll
    for (int cb = 0; cb < 8; ++cb) {
      acc[cb] = vz;
#pragma unroll
      for (int s = 0; s < 2; ++s) {
        const short8 bfr = *reinterpret_cast<const short8*>(
            WBp + (((size_t)(h * 8 + cb) * 2 + s) * 64 + lane) * 8);
        acc[cb] = __builtin_amdgcn_mfma_f32_16x16x32_bf16(a[s], bfr, acc[cb], 0, 0, 0);
      }
    }
#pragma unroll
    for (int jb = 0; jb < 4; ++jb)
#pragma unroll
      for (int r = 0; r < 4; ++r) {
        const long node = t * 16 + r4 * 4 + r;
        const unsigned lo = f2b(acc[jb][r]);
        const unsigned hi = f2b(acc[jb + 4][r]);
        Pu[node * 128 + h * 64 + jb * 16 + c16] = lo | (hi << 16);
      }
  }
}

// ---- edge pass. MODE 1: BN1 sum/ssq of t' (no bias). MODE 2: apply+scatter.
// Weight B-fragments staged in LDS (shared by the block's 4 waves).
template <int MODE>
__global__ __launch_bounds__(256, 3)
void edge_k(const ushort* __restrict__ nbrT, const ushort* __restrict__ WBe,
            const unsigned* __restrict__ Pu, const int* __restrict__ self_idx,
            const int* __restrict__ nbr_idx, float* __restrict__ stats,
            float* __restrict__ summed, int ntiles) {
  const int tid = threadIdx.x;
  const int lane = tid & 63;
  const int c16 = lane & 15, r4 = lane >> 4;
  const long nw = (long)gridDim.x * 4;
  const f32x4 vz = {0.f, 0.f, 0.f, 0.f};

  __shared__ ushort wbs[8192];  // [cb<8][s<2][lane<64][8] = 16 KB
  {
    const uint4* src = (const uint4*)WBe;
    uint4* dst = (uint4*)wbs;
    for (int i = tid; i < 1024; i += 256) dst[i] = src[i];
  }
  __syncthreads();

  float sc[8], sh[8];
  if (MODE == 2) {
#pragma unroll
    for (int cb = 0; cb < 8; ++cb) {
      sc[cb] = stats[256 + cb * 16 + c16];
      sh[cb] = stats[384 + cb * 16 + c16];
    }
  }
  float sum[8], ssq[8];
#pragma unroll
  for (int cb = 0; cb < 8; ++cb) { sum[cb] = 0.f; ssq[cb] = 0.f; }

  long t = (long)blockIdx.x * 4 + (tid >> 6);
  int se[4], ne[4];
  if (t < ntiles) {
#pragma unroll
    for (int r = 0; r < 4; ++r) {
      se[r] = self_idx[t * 16 + r4 * 4 + r];
      ne[r] = nbr_idx[t * 16 + r4 * 4 + r];
    }
  }
  while (t < ntiles) {
    // A-fragments (address dep on t only)
    const short8 a0 = *reinterpret_cast<const short8*>(nbrT + (t * 2) * 512 + lane * 8);
    const short8 a1 = *reinterpret_cast<const short8*>(nbrT + (t * 2 + 1) * 512 + lane * 8);
    // issue all 32 gathers (indices prefetched last iteration)
    unsigned gs[4][4], gn[4][4];
#pragma unroll
    for (int jb = 0; jb < 4; ++jb)
#pragma unroll
      for (int r = 0; r < 4; ++r) {
        gs[jb][r] = Pu[(long)se[r] * 128 + jb * 16 + c16];
        gn[jb][r] = Pu[(long)ne[r] * 128 + 64 + jb * 16 + c16];
      }
    // prefetch next tile's indices
    const long t2 = t + nw;
    int se2[4] = {0, 0, 0, 0}, ne2[4] = {0, 0, 0, 0};
    if (t2 < ntiles) {
#pragma unroll
      for (int r = 0; r < 4; ++r) {
        se2[r] = self_idx[t2 * 16 + r4 * 4 + r];
        ne2[r] = nbr_idx[t2 * 16 + r4 * 4 + r];
      }
    }
    // MFMA while gathers are in flight (B-fragments from LDS)
    f32x4 acc[8];
#pragma unroll
    for (int cb = 0; cb < 8; ++cb) {
      const short8 w0 = *reinterpret_cast<const short8*>(wbs + ((cb * 2 + 0) * 64 + lane) * 8);
      const short8 w1 = *reinterpret_cast<const short8*>(wbs + ((cb * 2 + 1) * 64 + lane) * 8);
      acc[cb] = __builtin_amdgcn_mfma_f32_16x16x32_bf16(a0, w0, vz, 0, 0, 0);
      acc[cb] = __builtin_amdgcn_mfma_f32_16x16x32_bf16(a1, w1, acc[cb], 0, 0, 0);
    }
#pragma unroll
    for (int jb = 0; jb < 4; ++jb)
#pragma unroll
      for (int r = 0; r < 4; ++r) {
        const unsigned ds = gs[jb][r], dn = gn[jb][r];
        const float tf = acc[jb][r]     + b2f((ushort)ds)         + b2f((ushort)dn);
        const float tc = acc[jb + 4][r] + b2f((ushort)(ds >> 16)) + b2f((ushort)(dn >> 16));
        if (MODE == 1) {
          sum[jb] += tf;     ssq[jb]     = fmaf(tf, tf, ssq[jb]);
          sum[jb + 4] += tc; ssq[jb + 4] = fmaf(tc, tc, ssq[jb + 4]);
        } else {
          const float uf = fmaf(tf, sc[jb], sh[jb]);
          const float uc = fmaf(tc, sc[jb + 4], sh[jb + 4]);
          atomicAdd(&summed[(long)se[r] * 64 + jb * 16 + c16],
                    sigmoid_f(uf) * softplus_f(uc));
        }
      }
    t = t2;
#pragma unroll
    for (int r = 0; r < 4; ++r) { se[r] = se2[r]; ne[r] = ne2[r]; }
  }

  if (MODE == 1) {
#pragma unroll
    for (int cb = 0; cb < 8; ++cb) {
      float s = sum[cb], q = ssq[cb];
      s += __shfl_xor(s, 16); q += __shfl_xor(q, 16);
      s += __shfl_xor(s, 32); q += __shfl_xor(q, 32);
      if (lane < 16) {
        atomicAdd(&stats[cb * 16 + lane], s);
        atomicAdd(&stats[128 + cb * 16 + lane], q);
      }
    }
  }
}

// fin1: stats of t' (no fc bias). var invariant to bias; mean = mean' + bias.
// shift folds fc bias: u = t'*sc + (b_bn - (mean'+bias)*sc).
__global__ void fin1_k(float* __restrict__ stats, const float* __restrict__ g,
                       const float* __restrict__ b, const float* __restrict__ fcb, int E) {
  const int c = threadIdx.x;  // 0..127
  const float meanp = stats[c] / (float)E;
  const float var = stats[128 + c] / (float)E - meanp * meanp;
  const float sc = g[c] * rsqrtf(var + 1e-5f);
  stats[256 + c] = sc;
  stats[384 + c] = fmaf(-(meanp + fcb[c]), sc, b[c]);
}

__global__ void bn2_stats_k(const float* __restrict__ summed, float* __restrict__ stats, int N) {
  const int tid = threadIdx.x;
  const int j = tid & 63;
  const int r = tid >> 6;
  float s = 0.f, q = 0.f;
  for (long n = (long)blockIdx.x * 4 + r; n < N; n += (long)gridDim.x * 4) {
    const float v = summed[n * 64 + j];
    s += v; q = fmaf(v, v, q);
  }
  __shared__ float2 red[256];
  red[tid] = make_float2(s, q);
  __syncthreads();
  if (tid < 64) {
    const float2 a = red[tid], b2 = red[tid + 64], c = red[tid + 128], d = red[tid + 192];
    atomicAdd(&stats[512 + tid], a.x + b2.x + c.x + d.x);
    atomicAdd(&stats[576 + tid], a.y + b2.y + c.y + d.y);
  }
}

__global__ void fin2_k(float* __restrict__ stats, const float* __restrict__ g,
                       const float* __restrict__ b, int N) {
  const int c = threadIdx.x;  // 0..63
  const float mean = stats[512 + c] / (float)N;
  const float var = stats[576 + c] / (float)N - mean * mean;
  const float sc = g[c] * rsqrtf(var + 1e-5f);
  stats[640 + c] = sc;
  stats[704 + c] = fmaf(-mean, sc, b[c]);
}

__global__ void upd_k(const float* __restrict__ x, const float* __restrict__ summed,
                      const float* __restrict__ stats, float* __restrict__ dst,
                      ushort* __restrict__ xb, int total) {
  const int idx = blockIdx.x * 256 + threadIdx.x;
  if (idx >= total) return;
  const int j = idx & 63;
  const float v = softplus_f(x[idx] + fmaf(summed[idx], stats[640 + j], stats[704 + j]));
  dst[idx] = v;
  xb[idx] = f2b(v);
}

extern "C" void kernel_launch(void* const* d_in, const int* in_sizes, int n_in,
                              void* d_out, int out_size, void* d_ws, size_t ws_size,
                              hipStream_t stream) {
  const float* atom_fea = (const float*)d_in[0];
  const float* nbr_fea  = (const float*)d_in[1];
  const int*   self_idx = (const int*)d_in[2];
  const int*   nbr_idx  = (const int*)d_in[3];
  const float* emb_W    = (const float*)d_in[4];
  const float* emb_b    = (const float*)d_in[5];
  const float* fc_W     = (const float*)d_in[6];
  const float* fc_b     = (const float*)d_in[7];
  const float* bn1_g    = (const float*)d_in[8];
  const float* bn1_b    = (const float*)d_in[9];
  const float* bn2_g    = (const float*)d_in[10];
  const float* bn2_b    = (const float*)d_in[11];
  float* out = (float*)d_out;

  const int N = in_sizes[0] / 92;
  const int E = in_sizes[2];
  const int ntilesE = (E + 15) / 16;
  const int ntilesN = (N + 15) / 16;

  unsigned char* base = (unsigned char*)d_ws;
  float* x      = (float*)base;                        base += (size_t)N * 64 * 4;
  unsigned* Pu  = (unsigned*)base;                     base += (size_t)N * 128 * 4;
  float* summed = (float*)base;                        base += (size_t)N * 64 * 4;
  float* stats  = (float*)base;                        base += 768 * 4;
  ushort* xb    = (ushort*)base;                       base += (size_t)N * 64 * 2;
  ushort* nbrT  = (ushort*)base;                       base += (size_t)ntilesE * 1024 * 2;
  ushort* WBe   = (ushort*)base;                       base += 32768 * 2;
  ushort* WBp   = (ushort*)base;                       base += 65536 * 2;
  ushort* WBm   = (ushort*)base;                       base += 6144 * 2;

  wconv_k<<<51, 256, 0, stream>>>(fc_W, emb_W, WBe, WBp, WBm);
  nbrconv_k<<<(ntilesE * 128 + 255) / 256, 256, 0, stream>>>(nbr_fea, nbrT, ntilesE, E);
  embed_mfma_k<<<512, 256, 0, stream>>>(atom_fea, WBm, emb_b, x, xb, ntilesN);

  for (int i = 0; i < 4; ++i) {
    const ushort* WBei = WBe + (size_t)i * 8192;
    const ushort* WBpi = WBp + (size_t)i * 16384;
    hipMemsetAsync(summed, 0, ((size_t)N * 64 + 768) * sizeof(float), stream);
    p_k<<<1024, 256, 0, stream>>>(xb, WBpi, Pu, ntilesN);
    edge_k<1><<<3072, 256, 0, stream>>>(nbrT, WBei, Pu, self_idx, nbr_idx, stats, summed, ntilesE);
    fin1_k<<<1, 128, 0, stream>>>(stats, bn1_g + (size_t)i * 128, bn1_b + (size_t)i * 128,
                                  fc_b + (size_t)i * 128, E);
    edge_k<2><<<3072, 256, 0, stream>>>(nbrT, WBei, Pu, self_idx, nbr_idx, stats, summed, ntilesE);
    bn2_stats_k<<<256, 256, 0, stream>>>(summed, stats, N);
    fin2_k<<<1, 64, 0, stream>>>(stats, bn2_g + (size_t)i * 64, bn2_b + (size_t)i * 64, N);
    float* dst = (i == 3) ? out : x;
    upd_k<<<(N * 64 + 255) / 256, 256, 0, stream>>>(x, summed, stats, dst, xb, N * 64);
  }
}